// Round 1
// baseline (176.080 us; speedup 1.0000x reference)
//
#include <hip/hip_runtime.h>
#include <hip/hip_bf16.h>
#include <stdint.h>

#define G_ 24
#define B_ 256
#define I_ 512
#define E_ 512
#define K_ (G_ * I_)   // 12288

typedef __bf16 bf16x8 __attribute__((ext_vector_type(8)));
typedef float f32x4 __attribute__((ext_vector_type(4)));

// ---------- input f32 -> bf16 ----------
__global__ void cvt_in_kernel(const float* __restrict__ in, __hip_bfloat16* __restrict__ out, int n4) {
  int idx = blockIdx.x * blockDim.x + threadIdx.x;
  if (idx >= n4) return;
  float4 v = reinterpret_cast<const float4*>(in)[idx];
  union { __hip_bfloat16 h[4]; uint2 u; } pk;
  pk.h[0] = __float2bfloat16(v.x);
  pk.h[1] = __float2bfloat16(v.y);
  pk.h[2] = __float2bfloat16(v.z);
  pk.h[3] = __float2bfloat16(v.w);
  reinterpret_cast<uint2*>(out)[idx] = pk.u;
}

// ---------- W[g][i][e] f32 -> Wt[g][e][i] bf16 ----------
__global__ void transpose_w_kernel(const float* __restrict__ W, __hip_bfloat16* __restrict__ Wt) {
  __shared__ float tile[32][33];
  const int g = blockIdx.z;
  const int i0 = blockIdx.x * 32;
  const int e0 = blockIdx.y * 32;
  const float* src = W + (size_t)g * (I_ * E_) + (size_t)(i0 + threadIdx.y) * E_ + e0 + threadIdx.x;
  #pragma unroll
  for (int r = 0; r < 32; r += 8)
    tile[threadIdx.y + r][threadIdx.x] = src[(size_t)r * E_];
  __syncthreads();
  __hip_bfloat16* dst = Wt + (size_t)g * (I_ * E_) + (size_t)(e0 + threadIdx.y) * I_ + i0 + threadIdx.x;
  #pragma unroll
  for (int r = 0; r < 32; r += 8)
    dst[(size_t)r * I_] = __float2bfloat16(tile[threadIdx.x][threadIdx.y + r]);
}

// ---------- main GEMM: out[b,h,e] = sum_k A[b,k] * Wt[(k/512 - h)%24][e][k%512] ----------
// BM=BN=128, BK=64, 4 waves (2x2), 16x16x32 bf16 MFMA, 4x4 frags/wave.
// LDS tiles [128 rows][64 cols] bf16 with XOR slot-swizzle: logical (row, slot)
// lives at linear chunk (row, slot ^ (row&7)); global_load_lds dest stays linear,
// global source uses the inverse (same) permutation.
__global__ __launch_bounds__(256) void gemm_kernel(
    const __hip_bfloat16* __restrict__ A,   // [256][12288]
    const __hip_bfloat16* __restrict__ Wt,  // [24][512(e)][512(i)]
    const float* __restrict__ bias,         // [512]
    float* __restrict__ out) {              // [256][24][512]

  __shared__ __align__(16) __hip_bfloat16 lds[2][2][128 * 64];  // 64 KB

  const int tid  = threadIdx.x;
  const int lane = tid & 63;
  const int wave = tid >> 6;
  const int h  = blockIdx.z;
  const int m0 = blockIdx.y * 128;
  const int n0 = blockIdx.x * 128;

  const int wr = wave >> 1;      // wave row (0..1) -> 64 rows
  const int wc = wave & 1;       // wave col (0..1) -> 64 cols
  const int rsel = lane & 15;
  const int q    = lane >> 4;

  f32x4 acc[4][4];
  #pragma unroll
  for (int i = 0; i < 4; ++i)
    #pragma unroll
    for (int j = 0; j < 4; ++j)
      acc[i][j] = (f32x4){0.f, 0.f, 0.f, 0.f};

  const int NT = K_ / 64;  // 192 k-steps

  auto stage = [&](int t, int buf) {
    const int g  = t >> 3;          // 512/64 = 8 k-steps per g
    const int i0 = (t & 7) * 64;
    int gsrc = g - h; if (gsrc < 0) gsrc += G_;
    const __hip_bfloat16* Abase = A  + (size_t)m0 * K_ + (size_t)t * 64;
    const __hip_bfloat16* Bbase = Wt + (size_t)gsrc * (I_ * E_) + (size_t)n0 * I_ + i0;
    #pragma unroll
    for (int j = 0; j < 4; ++j) {
      int c    = j * 256 + tid;           // 16B chunk id, 1024 chunks per tile
      int row  = c >> 3;                  // 8 chunks per 128B row
      int slot = (c & 7) ^ (row & 7);     // inverse-swizzled source slot
      const __hip_bfloat16* ga = Abase + (size_t)row * K_ + slot * 8;
      const __hip_bfloat16* gb = Bbase + (size_t)row * I_ + slot * 8;
      __hip_bfloat16* la = &lds[buf][0][(size_t)(j * 256 + wave * 64) * 8];
      __hip_bfloat16* lb = &lds[buf][1][(size_t)(j * 256 + wave * 64) * 8];
      __builtin_amdgcn_global_load_lds((const __attribute__((address_space(1))) void*)ga,
                                       (__attribute__((address_space(3))) void*)la, 16, 0, 0);
      __builtin_amdgcn_global_load_lds((const __attribute__((address_space(1))) void*)gb,
                                       (__attribute__((address_space(3))) void*)lb, 16, 0, 0);
    }
  };

  int cur = 0;
  stage(0, 0);

  for (int t = 0; t < NT; ++t) {
    if (t + 1 < NT) {
      stage(t + 1, cur ^ 1);
      asm volatile("s_waitcnt vmcnt(8)" ::: "memory");  // wait stage(t) only; keep 8 in flight
    } else {
      asm volatile("s_waitcnt vmcnt(0)" ::: "memory");
    }
    __builtin_amdgcn_s_barrier();
    asm volatile("" ::: "memory");

    const __hip_bfloat16* Al = &lds[cur][0][0];
    const __hip_bfloat16* Bl = &lds[cur][1][0];
    #pragma unroll
    for (int kk = 0; kk < 2; ++kk) {          // two K=32 MFMA blocks per BK=64
      const int kslot = kk * 4 + q;           // 16B slot index (0..7)
      bf16x8 af[4], bfr[4];
      #pragma unroll
      for (int mi = 0; mi < 4; ++mi) {
        int r = wr * 64 + mi * 16 + rsel;
        int lin = kslot ^ (r & 7);
        af[mi] = *(const bf16x8*)(Al + (size_t)r * 64 + lin * 8);
      }
      #pragma unroll
      for (int ni = 0; ni < 4; ++ni) {
        int r = wc * 64 + ni * 16 + rsel;
        int lin = kslot ^ (r & 7);
        bfr[ni] = *(const bf16x8*)(Bl + (size_t)r * 64 + lin * 8);
      }
      #pragma unroll
      for (int mi = 0; mi < 4; ++mi)
        #pragma unroll
        for (int ni = 0; ni < 4; ++ni)
          acc[mi][ni] = __builtin_amdgcn_mfma_f32_16x16x32_bf16(af[mi], bfr[ni], acc[mi][ni], 0, 0, 0);
    }

    asm volatile("s_waitcnt lgkmcnt(0)" ::: "memory");
    __builtin_amdgcn_s_barrier();
    asm volatile("" ::: "memory");
    cur ^= 1;
  }

  // epilogue: C[row=M, col=N]; C/D layout col=lane&15, row=(lane>>4)*4+reg
  #pragma unroll
  for (int mi = 0; mi < 4; ++mi) {
    #pragma unroll
    for (int ni = 0; ni < 4; ++ni) {
      int col  = n0 + wc * 64 + ni * 16 + (lane & 15);
      float bv = bias[col];
      int rowb = m0 + wr * 64 + mi * 16 + (lane >> 4) * 4;
      float* o = out + (size_t)rowb * (G_ * E_) + (size_t)h * E_ + col;
      #pragma unroll
      for (int r = 0; r < 4; ++r)
        o[(size_t)r * (G_ * E_)] = acc[mi][ni][r] + bv;
    }
  }
}

extern "C" void kernel_launch(void* const* d_in, const int* in_sizes, int n_in,
                              void* d_out, int out_size, void* d_ws, size_t ws_size,
                              hipStream_t stream) {
  const float* in   = (const float*)d_in[0];
  const float* w    = (const float*)d_in[1];
  const float* bias = (const float*)d_in[2];
  float* out = (float*)d_out;

  __hip_bfloat16* A_bf = (__hip_bfloat16*)d_ws;                                   // 12.58 MB
  __hip_bfloat16* Wt   = (__hip_bfloat16*)((char*)d_ws + (size_t)B_ * K_ * 2);    // 12.58 MB

  const int n4 = (B_ * K_) / 4;  // 786432 float4 groups
  cvt_in_kernel<<<n4 / 256, 256, 0, stream>>>(in, A_bf, n4);
  transpose_w_kernel<<<dim3(E_ / 32, I_ / 32, G_), dim3(32, 8), 0, stream>>>(w, Wt);
  gemm_kernel<<<dim3(E_ / 128, B_ / 128, G_), 256, 0, stream>>>(A_bf, Wt, bias, out);
}

// Round 2
// 123.403 us; speedup vs baseline: 1.4269x; 1.4269x over previous
//
#include <hip/hip_runtime.h>
#include <hip/hip_bf16.h>
#include <stdint.h>

#define G_ 24
#define B_ 256
#define I_ 512
#define E_ 512
#define K_ (G_ * I_)   // 12288
#define SPLITK 2
#define NT_SPLIT (K_ / 64 / SPLITK)   // 96 k-steps per split

typedef __bf16 bf16x8 __attribute__((ext_vector_type(8)));
typedef float f32x4 __attribute__((ext_vector_type(4)));

// ---------- input f32 -> bf16 ----------
__global__ void cvt_in_kernel(const float* __restrict__ in, __hip_bfloat16* __restrict__ out, int n4) {
  int idx = blockIdx.x * blockDim.x + threadIdx.x;
  if (idx >= n4) return;
  float4 v = reinterpret_cast<const float4*>(in)[idx];
  union { __hip_bfloat16 h[4]; uint2 u; } pk;
  pk.h[0] = __float2bfloat16(v.x);
  pk.h[1] = __float2bfloat16(v.y);
  pk.h[2] = __float2bfloat16(v.z);
  pk.h[3] = __float2bfloat16(v.w);
  reinterpret_cast<uint2*>(out)[idx] = pk.u;
}

// ---------- W[g][i][e] f32 -> Wt[g][e][i] bf16 ----------
__global__ void transpose_w_kernel(const float* __restrict__ W, __hip_bfloat16* __restrict__ Wt) {
  __shared__ float tile[32][33];
  const int g = blockIdx.z;
  const int i0 = blockIdx.x * 32;
  const int e0 = blockIdx.y * 32;
  const float* src = W + (size_t)g * (I_ * E_) + (size_t)(i0 + threadIdx.y) * E_ + e0 + threadIdx.x;
  #pragma unroll
  for (int r = 0; r < 32; r += 8)
    tile[threadIdx.y + r][threadIdx.x] = src[(size_t)r * E_];
  __syncthreads();
  __hip_bfloat16* dst = Wt + (size_t)g * (I_ * E_) + (size_t)(e0 + threadIdx.y) * I_ + i0 + threadIdx.x;
  #pragma unroll
  for (int r = 0; r < 32; r += 8)
    dst[(size_t)r * I_] = __float2bfloat16(tile[threadIdx.x][threadIdx.y + r]);
}

// ---------- out[b][h][e] = bias[e] ----------
__global__ void init_out_kernel(const float* __restrict__ bias, float* __restrict__ out, int n4) {
  int idx = blockIdx.x * blockDim.x + threadIdx.x;
  if (idx >= n4) return;
  int e4 = idx & 127;  // (E/4)=128 float4 per (b,h) row
  reinterpret_cast<float4*>(out)[idx] = reinterpret_cast<const float4*>(bias)[e4];
}

// ---------- main GEMM with split-K=2, atomic accumulation ----------
// out[b,h,e] += sum_k A[b,k] * Wt[(k/512 - h)%24][e][k%512]
// BM=128, BN=64, BK=64, 4 waves (2x2), wave tile 64x32 (4x2 frags of 16x16x32).
// LDS: A [128][64], B [64][64] bf16, double-buffered = 48 KB -> 3 WGs/CU.
// XOR slot-swizzle: logical (row, slot) lives at linear chunk (row, slot^(row&7));
// global_load_lds dest stays linear, global source uses the inverse permutation.
__global__ __launch_bounds__(256) void gemm_kernel(
    const __hip_bfloat16* __restrict__ A,   // [256][12288]
    const __hip_bfloat16* __restrict__ Wt,  // [24][512(e)][512(i)]
    float* __restrict__ out) {              // [256][24][512], pre-init'd with bias

  __shared__ __align__(16) __hip_bfloat16 ldsA[2][128 * 64];  // 32 KB
  __shared__ __align__(16) __hip_bfloat16 ldsB[2][64 * 64];   // 16 KB

  const int tid  = threadIdx.x;
  const int lane = tid & 63;
  const int wave = tid >> 6;
  const int h     = blockIdx.z >> 1;
  const int split = blockIdx.z & 1;
  const int m0 = blockIdx.y * 128;
  const int n0 = blockIdx.x * 64;

  const int wr = wave >> 1;      // wave row (0..1) -> 64 rows
  const int wc = wave & 1;       // wave col (0..1) -> 32 cols
  const int rsel = lane & 15;
  const int q    = lane >> 4;

  f32x4 acc[4][2];
  #pragma unroll
  for (int i = 0; i < 4; ++i)
    #pragma unroll
    for (int j = 0; j < 2; ++j)
      acc[i][j] = (f32x4){0.f, 0.f, 0.f, 0.f};

  auto stage = [&](int t, int buf) {
    const int g  = t >> 3;          // 8 k-steps per g
    const int i0 = (t & 7) * 64;
    int gsrc = g - h; if (gsrc < 0) gsrc += G_;
    const __hip_bfloat16* Abase = A  + (size_t)m0 * K_ + (size_t)t * 64;
    const __hip_bfloat16* Bbase = Wt + (size_t)gsrc * (I_ * E_) + (size_t)n0 * I_ + i0;
    #pragma unroll
    for (int j = 0; j < 4; ++j) {   // A: 1024 chunks
      int c    = j * 256 + tid;
      int row  = c >> 3;
      int slot = (c & 7) ^ (row & 7);
      const __hip_bfloat16* ga = Abase + (size_t)row * K_ + slot * 8;
      __builtin_amdgcn_global_load_lds((const __attribute__((address_space(1))) void*)ga,
          (__attribute__((address_space(3))) void*)&ldsA[buf][(size_t)c * 8], 16, 0, 0);
    }
    #pragma unroll
    for (int j = 0; j < 2; ++j) {   // B: 512 chunks
      int c    = j * 256 + tid;
      int row  = c >> 3;
      int slot = (c & 7) ^ (row & 7);
      const __hip_bfloat16* gb = Bbase + (size_t)row * I_ + slot * 8;
      __builtin_amdgcn_global_load_lds((const __attribute__((address_space(1))) void*)gb,
          (__attribute__((address_space(3))) void*)&ldsB[buf][(size_t)c * 8], 16, 0, 0);
    }
  };

  const int t0 = split * NT_SPLIT;
  int cur = 0;
  stage(t0, 0);

  for (int lt = 0; lt < NT_SPLIT; ++lt) {
    const int t = t0 + lt;
    if (lt + 1 < NT_SPLIT) {
      stage(t + 1, cur ^ 1);
      asm volatile("s_waitcnt vmcnt(6)" ::: "memory");  // wait stage(t) only; keep 6 in flight
    } else {
      asm volatile("s_waitcnt vmcnt(0)" ::: "memory");
    }
    __builtin_amdgcn_s_barrier();
    asm volatile("" ::: "memory");

    const __hip_bfloat16* Al = &ldsA[cur][0];
    const __hip_bfloat16* Bl = &ldsB[cur][0];
    #pragma unroll
    for (int kk = 0; kk < 2; ++kk) {          // two K=32 MFMA blocks per BK=64
      const int kslot = kk * 4 + q;           // 16B slot index (0..7)
      bf16x8 af[4], bfr[2];
      #pragma unroll
      for (int mi = 0; mi < 4; ++mi) {
        int r = wr * 64 + mi * 16 + rsel;
        int lin = kslot ^ (r & 7);
        af[mi] = *(const bf16x8*)(Al + (size_t)r * 64 + lin * 8);
      }
      #pragma unroll
      for (int ni = 0; ni < 2; ++ni) {
        int r = wc * 32 + ni * 16 + rsel;
        int lin = kslot ^ (r & 7);
        bfr[ni] = *(const bf16x8*)(Bl + (size_t)r * 64 + lin * 8);
      }
      #pragma unroll
      for (int mi = 0; mi < 4; ++mi)
        #pragma unroll
        for (int ni = 0; ni < 2; ++ni)
          acc[mi][ni] = __builtin_amdgcn_mfma_f32_16x16x32_bf16(af[mi], bfr[ni], acc[mi][ni], 0, 0, 0);
    }

    asm volatile("s_waitcnt lgkmcnt(0)" ::: "memory");
    __builtin_amdgcn_s_barrier();
    asm volatile("" ::: "memory");
    cur ^= 1;
  }

  // epilogue: C/D layout col=lane&15, row=(lane>>4)*4+reg; atomic split-K combine
  #pragma unroll
  for (int mi = 0; mi < 4; ++mi) {
    #pragma unroll
    for (int ni = 0; ni < 2; ++ni) {
      int col  = n0 + wc * 32 + ni * 16 + (lane & 15);
      int rowb = m0 + wr * 64 + mi * 16 + (lane >> 4) * 4;
      float* o = out + (size_t)rowb * (G_ * E_) + (size_t)h * E_ + col;
      #pragma unroll
      for (int r = 0; r < 4; ++r)
        atomicAdd(o + (size_t)r * (G_ * E_), acc[mi][ni][r]);
    }
  }
}

extern "C" void kernel_launch(void* const* d_in, const int* in_sizes, int n_in,
                              void* d_out, int out_size, void* d_ws, size_t ws_size,
                              hipStream_t stream) {
  const float* in   = (const float*)d_in[0];
  const float* w    = (const float*)d_in[1];
  const float* bias = (const float*)d_in[2];
  float* out = (float*)d_out;

  __hip_bfloat16* A_bf = (__hip_bfloat16*)d_ws;                                   // 6.29 MB
  __hip_bfloat16* Wt   = (__hip_bfloat16*)((char*)d_ws + (size_t)B_ * K_ * 2);    // 12.58 MB

  const int n4in  = (B_ * K_) / 4;        // 786432
  const int n4out = (B_ * G_ * E_) / 4;   // 786432
  cvt_in_kernel<<<n4in / 256, 256, 0, stream>>>(in, A_bf, n4in);
  transpose_w_kernel<<<dim3(E_ / 32, I_ / 32, G_), dim3(32, 8), 0, stream>>>(w, Wt);
  init_out_kernel<<<n4out / 256, 256, 0, stream>>>(bias, out, n4out);
  gemm_kernel<<<dim3(E_ / 64, B_ / 128, G_ * SPLITK), 256, 0, stream>>>(A_bf, Wt, out);
}